// Round 9
// baseline (277.121 us; speedup 1.0000x reference)
//
#include <hip/hip_runtime.h>
#include <math.h>

#define KK 48
#define TT 1024
#define BB 512
#define START_TAG 46
#define END_TAG 47
#define NSEG 16
#define OWN (TT / NSEG)     // 64 owned steps per segment wave
#define WARM 12             // warm-up steps for segments 1..15
#define NTHR (NSEG * 64)    // 1024 threads = 16 waves (one sentence-group)
#define NGRP (BB / 16)      // 32 sentence-groups (16 sentences per wave, MFMA N=16)

typedef _Float16 h2 __attribute__((ext_vector_type(2)));
typedef _Float16 f16x4 __attribute__((ext_vector_type(4)));
typedef float f32x4 __attribute__((ext_vector_type(4)));

// MFMA intrinsic is device-only: __has_builtin is FALSE in the host pass
// (R17 failed compiling for host). Host gets an inert stub — it only parses.
#if defined(__HIP_DEVICE_COMPILE__)
  #if __has_builtin(__builtin_amdgcn_mfma_f32_16x16x16f16)
    #define MFMA16(A, B, C) __builtin_amdgcn_mfma_f32_16x16x16f16((A), (B), (C), 0, 0, 0)
  #elif __has_builtin(__builtin_amdgcn_mfma_f32_16x16x16_f16)
    #define MFMA16(A, B, C) __builtin_amdgcn_mfma_f32_16x16x16_f16((A), (B), (C), 0, 0, 0)
  #else
    #error "no 16x16x16 f16 mfma on this target"
  #endif
#else
  #define MFMA16(A, B, C) (C)
#endif

// cvt_pkrtz returns __fp16x2; bit_cast to our h2 (same 4 bytes).
__device__ __forceinline__ h2 pkrtz(float a, float b) {
    return __builtin_bit_cast(h2, __builtin_amdgcn_cvt_pkrtz(a, b));
}

// ---------------------------------------------------------------------------
// R18 (= R16 algorithm, compile-fixed twice): MFMA-batched recurrence — the
// broadcast disappears into the matrix pipe.
//
// R15 closed the scalar-path story: issue-bound at 272 cyc/step/wave, ~70% of
// which is the 24-readlane broadcast (8 cyc each); LDS-memory broadcast broke
// twice (R10/R13), bpermute 1.8x worse (R14), occupancy maxed (8/SIMD).
// R18 batches 16 sentences per wave as MFMA columns: alpha_new = E * Alpha
// via v_mfma_f32_16x16x16_f16, K=48 = 3 tiles x 3 chunks = 9 MFMAs/step.
// KEY LAYOUT FACT: D-frag layout == B-frag layout for 16x16x16 (col=lane&15,
// row/k=(lane>>4)*4+reg), so D (scaled, x ef, cvt to f16) feeds the next
// step's B operand IN PLACE — no shuffles, no LDS, no broadcast. Per-column
// pow-2 norm ledger (exact ints) needs only 1 __shfl/step (row-0 ref value).
// E in f16 (same systematic as R9-R15, absmax 32); per-step scale mechanics
// identical. Segmentation as R15: NSEG=16, WARM=12, in-block combine; block
// = 16 waves = one 16-sentence group; grid = 32 blocks (validation round —
// spread/split comes next if layout verifies).
// Predicted: 15-28 us dispatch; MfmaUtil > 0; absmax ~32.
// ---------------------------------------------------------------------------

template <bool EXACT>
__device__ __forceinline__ void run_seg(const float* __restrict__ fbl,
                                        const float* __restrict__ trans,
                                        int lane, int g4, int r0, int nsteps,
                                        float (&wv)[3][4], int& esumO, int& eswmO,
                                        float& q0O) {
    // A-frags (constant): A[m][c] holds E-tile rows 16m+(lane&15), k 16c+4*g4+j
    f16x4 Af[3][3];
    #pragma unroll
    for (int m = 0; m < 3; ++m) {
        const int row = 16 * m + (lane & 15);
        #pragma unroll
        for (int c = 0; c < 3; ++c) {
            #pragma unroll
            for (int j = 0; j < 4; ++j)
                Af[m][c][j] = (_Float16)__expf(trans[row * KK + 16 * c + 4 * g4 + j]);
        }
    }

    // B-frags (state): alpha[k = 16c + 4*g4 + j][sent = lane&15], f16
    f16x4 bf[3];
    if (EXACT) {
        #pragma unroll
        for (int c = 0; c < 3; ++c) bf[c] = (f16x4)(_Float16)0.0f;
        if (g4 == 3) bf[2][2] = (_Float16)1.0f;   // k = 32+4*3+2 = 46 = START
    } else {
        #pragma unroll
        for (int c = 0; c < 3; ++c) bf[c] = (f16x4)(_Float16)1.0f;  // all-ones
    }

    int esum = 0, eswm = 0;
    float q0v = 1.0f;

    // feats prefetch buffers: ft[m] = feats[t][16m+4*g4 .. +3] (16B aligned)
    f32x4 ftA[3], ftB[3];
    #pragma unroll
    for (int m = 0; m < 3; ++m)
        ftA[m] = *(const f32x4*)(fbl + (size_t)r0 * KK + 16 * m + 4 * g4);

    auto STEP = [&](f32x4(&ftU)[3], f32x4(&ftL)[3], int st) {
        // prefetch next step's feats (independent of the chain)
        int tn = r0 + st + 1;
        if (tn > TT - 1) tn = TT - 1;
        #pragma unroll
        for (int m = 0; m < 3; ++m)
            ftL[m] = *(const f32x4*)(fbl + (size_t)tn * KK + 16 * m + 4 * g4);
        // ef for current step
        float ef[3][4];
        #pragma unroll
        for (int m = 0; m < 3; ++m)
            #pragma unroll
            for (int r = 0; r < 4; ++r) ef[m][r] = __expf(ftU[m][r]);
        // D = E * Alpha : 3 output tiles x 3 K-chunks
        const f32x4 z = {0.f, 0.f, 0.f, 0.f};
        f32x4 a0 = MFMA16(Af[0][0], bf[0], z);
        f32x4 a1 = MFMA16(Af[1][0], bf[0], z);
        f32x4 a2 = MFMA16(Af[2][0], bf[0], z);
        a0 = MFMA16(Af[0][1], bf[1], a0);
        a1 = MFMA16(Af[1][1], bf[1], a1);
        a2 = MFMA16(Af[2][1], bf[1], a2);
        a0 = MFMA16(Af[0][2], bf[2], a0);
        a1 = MFMA16(Af[1][2], bf[2], a1);
        a2 = MFMA16(Af[2][2], bf[2], a2);
        // alpha_raw = D .* ef  (per-lane: rows 16m+4*g4+r of own sentence)
        #pragma unroll
        for (int r = 0; r < 4; ++r) {
            wv[0][r] = a0[r] * ef[0][r];
            wv[1][r] = a1[r] * ef[1][r];
            wv[2][r] = a2[r] * ef[2][r];
        }
        // per-sentence pow-2 norm: ref = row-0 raw value of own column
        float ref = __shfl(wv[0][0], lane & 15, 64);
        int eb = ((__float_as_int(ref) >> 23) & 0xff) - 127;
        esum += eb;
        float sc = __int_as_float((127 - eb) << 23);
        #pragma unroll
        for (int m = 0; m < 3; ++m)
            #pragma unroll
            for (int r = 0; r < 4; ++r) wv[m][r] *= sc;
        if (!EXACT && st == WARM - 1) { eswm = esum; q0v = ref * sc; }
        // pack scaled alpha -> next B-frags (same lane, D-layout == B-layout)
        #pragma unroll
        for (int m = 0; m < 3; ++m) {
            h2 lo = pkrtz(wv[m][0], wv[m][1]);
            h2 hi = pkrtz(wv[m][2], wv[m][3]);
            bf[m][0] = lo.x; bf[m][1] = lo.y; bf[m][2] = hi.x; bf[m][3] = hi.y;
        }
    };

    for (int st = 0; st < nsteps; st += 2) {   // nsteps is even (64 or 76)
        STEP(ftA, ftB, st);
        STEP(ftB, ftA, st + 1);
    }
    esumO = esum; eswmO = eswm; q0O = q0v;
}

__global__ __launch_bounds__(NTHR)
void crf_kernel(const float* __restrict__ feats,
                const float* __restrict__ trans,
                const int* __restrict__ tags,
                float* __restrict__ out) {
    const int g = blockIdx.x;           // sentence-group (16 sentences)
    const int tid = threadIdx.x;
    const int seg = tid >> 6;           // segment index 0..15 (one wave each)
    const int lane = tid & 63;
    const int g4 = lane >> 4;           // row-quad group within fragments
    const int sb = g * 16 + (lane & 15);
    const float* fbl = feats + (size_t)sb * TT * KK;

    __shared__ float shU[NSEG][16][KK];   // final alpha direction per (seg, sent)
    __shared__ int shO[NSEG][16];         // owned-step ledgers
    __shared__ float shQ0[NSEG][16];      // row-0 residual at warm boundary

    float wv[3][4];
    int esum, eswm; float q0v;
    if (seg == 0) run_seg<true >(fbl, trans, lane, g4, 0, OWN, wv, esum, eswm, q0v);
    else          run_seg<false>(fbl, trans, lane, g4, seg * OWN - WARM, OWN + WARM,
                                 wv, esum, eswm, q0v);

    #pragma unroll
    for (int m = 0; m < 3; ++m)
        #pragma unroll
        for (int r = 0; r < 4; ++r)
            shU[seg][lane & 15][16 * m + 4 * g4 + r] = wv[m][r];
    if (lane < 16) { shO[seg][lane] = esum - eswm; shQ0[seg][lane] = q0v; }
    __syncthreads();

    // ---- combine: wave `seg` finishes sentence g*16 + seg ----
    {
        const int w = seg;
        const int sent = g * 16 + w;
        const int* tg = tags + (size_t)sent * TT;
        // Z tail: sum_i exp(trans[END][i]) * u_last[i]
        float val = (lane < KK) ? __expf(trans[END_TAG * KK + lane]) * shU[NSEG - 1][w][lane]
                                : 0.0f;
        #pragma unroll
        for (int off = 32; off; off >>= 1) val += __shfl_xor(val, off, 64);
        // ledger + scalar stitches (lane-parallel)
        float stv = 0.0f;
        if (lane >= 1 && lane < NSEG)
            stv = __logf(shU[lane - 1][w][0]) - __logf(shQ0[lane][w]);
        if (lane < NSEG)
            stv += (float)shO[lane][w] * 0.6931471805599453f;
        #pragma unroll
        for (int off = 32; off; off >>= 1) stv += __shfl_xor(stv, off, 64);
        // gold score for sentence `sent`
        float gacc = 0.0f;
        const float* fbs = feats + (size_t)sent * TT * KK;
        #pragma unroll
        for (int it = 0; it < TT / 64; ++it) {
            int t = lane + it * 64;
            int cur = tg[t];
            int prev = (t == 0) ? START_TAG : tg[t - 1];
            gacc += trans[cur * KK + prev] + fbs[(size_t)t * KK + cur];
        }
        #pragma unroll
        for (int off = 32; off; off >>= 1) gacc += __shfl_xor(gacc, off, 64);
        if (lane == 0) {
            float gold = gacc + trans[END_TAG * KK + tg[TT - 1]];
            out[sent] = __logf(val) + stv - gold;
        }
    }
}

extern "C" void kernel_launch(void* const* d_in, const int* in_sizes, int n_in,
                              void* d_out, int out_size, void* d_ws, size_t ws_size,
                              hipStream_t stream) {
    const float* feats = (const float*)d_in[0];
    const float* trans = (const float*)d_in[1];
    const int* tags = (const int*)d_in[2];
    float* out = (float*)d_out;

    crf_kernel<<<NGRP, NTHR, 0, stream>>>(feats, trans, tags, out);
}

// Round 10
// 189.337 us; speedup vs baseline: 1.4636x; 1.4636x over previous
//
#include <hip/hip_runtime.h>
#include <math.h>

#define KK 48
#define TT 1024
#define BB 512
#define START_TAG 46
#define END_TAG 47
#define NSEG 16
#define OWN (TT / NSEG)     // 64 owned steps per segment wave
#define WARM 16             // warm-up steps for segments 1..15 (div by DEPTH)
#define DEPTH 8             // feats prefetch depth (ring buffer)
#define NGRP (BB / 16)      // 32 sentence-groups of 16 (MFMA N=16)
#define NPAIR (NGRP * NSEG) // 512 (group, segment) blocks
#define WSF 50              // floats per (pair, sent) partial: 48 U + O + q0

typedef _Float16 h2 __attribute__((ext_vector_type(2)));
typedef _Float16 f16x4 __attribute__((ext_vector_type(4)));
typedef float f32x4 __attribute__((ext_vector_type(4)));

// MFMA intrinsic is device-only: __has_builtin is FALSE in the host pass.
#if defined(__HIP_DEVICE_COMPILE__)
  #if __has_builtin(__builtin_amdgcn_mfma_f32_16x16x16f16)
    #define MFMA16(A, B, C) __builtin_amdgcn_mfma_f32_16x16x16f16((A), (B), (C), 0, 0, 0)
  #elif __has_builtin(__builtin_amdgcn_mfma_f32_16x16x16_f16)
    #define MFMA16(A, B, C) __builtin_amdgcn_mfma_f32_16x16x16_f16((A), (B), (C), 0, 0, 0)
  #else
    #error "no 16x16x16 f16 mfma on this target"
  #endif
#else
  #define MFMA16(A, B, C) (C)
#endif

__device__ __forceinline__ h2 pkrtz(float a, float b) {
    return __builtin_bit_cast(h2, __builtin_amdgcn_cvt_pkrtz(a, b));
}

// ---------------------------------------------------------------------------
// R19: spread + deep prefetch. R18 verified the MFMA recurrence (absmax 32,
// D-frag==B-frag in-place feedback) but ran 170 us at VALUBusy 3%, HBM 533
// GB/s = 1/16 of achievable: the 16-sentence gather (stride 3*2^16 B) makes
// every load 16 same-channel transactions (addresses equal mod 2^16) that
// serialize, ~5000 cyc effective latency, with only 32 CUs and 1-step
// prefetch to hide it. R19 keeps the verified datapath and attacks the load
// path: (1) one segment-wave per 64-thr block, 512 blocks over 256 CUs
// (partials to d_ws, 1.64 MB; tiny combine kernel second — stream-ordered);
// (2) prefetch ring DEPTH=8 (compile-time indices), ~24 loads/wave in
// flight. WARM 12->16 (divisible by 8). Numerics identical otherwise.
// Predicted: hbm_gbps 533 -> 2000+, main ~25-45 us + combine ~5-15 us;
// absmax 32. Falsifier: HBM stuck ~500 => channel-serialization is
// aggregate-fundamental -> next round transposes feats into d_ws.
// ---------------------------------------------------------------------------

template <bool EXACT>
__device__ __forceinline__ void run_seg(const float* __restrict__ fbl,
                                        const float* __restrict__ trans,
                                        int lane, int g4, int r0, int nsteps,
                                        float (&wv)[3][4], int& esumO, int& eswmO,
                                        float& q0O) {
    // A-frags (constant): A[m][c] holds E rows 16m+(lane&15), k 16c+4*g4+j
    f16x4 Af[3][3];
    #pragma unroll
    for (int m = 0; m < 3; ++m) {
        const int row = 16 * m + (lane & 15);
        #pragma unroll
        for (int c = 0; c < 3; ++c) {
            #pragma unroll
            for (int j = 0; j < 4; ++j)
                Af[m][c][j] = (_Float16)__expf(trans[row * KK + 16 * c + 4 * g4 + j]);
        }
    }

    // B-frags (state): alpha[k = 16c + 4*g4 + j][sent = lane&15], f16
    f16x4 bf[3];
    if (EXACT) {
        #pragma unroll
        for (int c = 0; c < 3; ++c) bf[c] = (f16x4)(_Float16)0.0f;
        if (g4 == 3) bf[2][2] = (_Float16)1.0f;   // k = 32+4*3+2 = 46 = START
    } else {
        #pragma unroll
        for (int c = 0; c < 3; ++c) bf[c] = (f16x4)(_Float16)1.0f;  // all-ones
    }

    int esum = 0, eswm = 0;
    float q0v = 1.0f;

    // prefetch ring: ft[j][m] = feats[r0+st..][16m+4g4 ..+3], depth DEPTH
    f32x4 ft[DEPTH][3];
    #pragma unroll
    for (int j = 0; j < DEPTH; ++j) {
        int t = r0 + j; if (t > TT - 1) t = TT - 1;
        #pragma unroll
        for (int m = 0; m < 3; ++m)
            ft[j][m] = *(const f32x4*)(fbl + (size_t)t * KK + 16 * m + 4 * g4);
    }

    for (int s0 = 0; s0 < nsteps; s0 += DEPTH) {
        #pragma unroll
        for (int j = 0; j < DEPTH; ++j) {
            const int st = s0 + j;
            // consume slot j
            float ef[3][4];
            #pragma unroll
            for (int m = 0; m < 3; ++m)
                #pragma unroll
                for (int r = 0; r < 4; ++r) ef[m][r] = __expf(ft[j][m][r]);
            // reload slot j with step st+DEPTH (independent of the chain)
            {
                int tn = r0 + st + DEPTH; if (tn > TT - 1) tn = TT - 1;
                #pragma unroll
                for (int m = 0; m < 3; ++m)
                    ft[j][m] = *(const f32x4*)(fbl + (size_t)tn * KK + 16 * m + 4 * g4);
            }
            // D = E * Alpha : 3 output tiles x 3 K-chunks
            const f32x4 z = {0.f, 0.f, 0.f, 0.f};
            f32x4 a0 = MFMA16(Af[0][0], bf[0], z);
            f32x4 a1 = MFMA16(Af[1][0], bf[0], z);
            f32x4 a2 = MFMA16(Af[2][0], bf[0], z);
            a0 = MFMA16(Af[0][1], bf[1], a0);
            a1 = MFMA16(Af[1][1], bf[1], a1);
            a2 = MFMA16(Af[2][1], bf[1], a2);
            a0 = MFMA16(Af[0][2], bf[2], a0);
            a1 = MFMA16(Af[1][2], bf[2], a1);
            a2 = MFMA16(Af[2][2], bf[2], a2);
            // alpha_raw = D .* ef
            #pragma unroll
            for (int r = 0; r < 4; ++r) {
                wv[0][r] = a0[r] * ef[0][r];
                wv[1][r] = a1[r] * ef[1][r];
                wv[2][r] = a2[r] * ef[2][r];
            }
            // per-sentence pow-2 norm: ref = row-0 raw value of own column
            float ref = __shfl(wv[0][0], lane & 15, 64);
            int eb = ((__float_as_int(ref) >> 23) & 0xff) - 127;
            esum += eb;
            float sc = __int_as_float((127 - eb) << 23);
            #pragma unroll
            for (int m = 0; m < 3; ++m)
                #pragma unroll
                for (int r = 0; r < 4; ++r) wv[m][r] *= sc;
            if (!EXACT && st == WARM - 1) { eswm = esum; q0v = ref * sc; }
            // pack scaled alpha -> next B-frags (D-layout == B-layout)
            #pragma unroll
            for (int m = 0; m < 3; ++m) {
                h2 lo = pkrtz(wv[m][0], wv[m][1]);
                h2 hi = pkrtz(wv[m][2], wv[m][3]);
                bf[m][0] = lo.x; bf[m][1] = lo.y; bf[m][2] = hi.x; bf[m][3] = hi.y;
            }
        }
    }
    esumO = esum; eswmO = eswm; q0O = q0v;
}

__global__ __launch_bounds__(64)
void crf_seg_kernel(const float* __restrict__ feats,
                    const float* __restrict__ trans,
                    float* __restrict__ ws) {
    const int pair = blockIdx.x;        // g*16 + seg
    const int g = pair >> 4;
    const int seg = pair & 15;
    const int lane = threadIdx.x & 63;
    const int g4 = lane >> 4;
    const float* fbl = feats + (size_t)(g * 16 + (lane & 15)) * TT * KK;

    float wv[3][4];
    int esum, eswm; float q0v;
    if (seg == 0) run_seg<true >(fbl, trans, lane, g4, 0, OWN, wv, esum, eswm, q0v);
    else          run_seg<false>(fbl, trans, lane, g4, seg * OWN - WARM, OWN + WARM,
                                 wv, esum, eswm, q0v);

    // partials: ws[(pair*16 + sent)*WSF + {0..47: U, 48: O, 49: q0}]
    float* base = ws + ((size_t)pair * 16 + (lane & 15)) * WSF;
    #pragma unroll
    for (int m = 0; m < 3; ++m)
        #pragma unroll
        for (int r = 0; r < 4; ++r)
            base[16 * m + 4 * g4 + r] = wv[m][r];
    if (lane < 16) {
        float* b2 = ws + ((size_t)pair * 16 + lane) * WSF;
        b2[48] = (float)(esum - eswm);   // exact: |O| << 2^24
        b2[49] = q0v;
    }
}

__global__ __launch_bounds__(64)
void crf_combine(const float* __restrict__ feats,
                 const float* __restrict__ trans,
                 const int* __restrict__ tags,
                 const float* __restrict__ ws,
                 float* __restrict__ out) {
    const int s = blockIdx.x;           // sentence
    const int g = s >> 4;
    const int sidx = s & 15;
    const int lane = threadIdx.x & 63;
    const int* tg = tags + (size_t)s * TT;
    const float* fbs = feats + (size_t)s * TT * KK;

    // Z tail: sum_i exp(trans[END][i]) * U_last[i]
    float val = 0.0f;
    if (lane < KK)
        val = __expf(trans[END_TAG * KK + lane]) *
              ws[(((size_t)g * 16 + 15) * 16 + sidx) * WSF + lane];
    #pragma unroll
    for (int off = 32; off; off >>= 1) val += __shfl_xor(val, off, 64);

    // ledgers + scalar stitches (lane-parallel over segments)
    float stv = 0.0f;
    if (lane >= 1 && lane < NSEG) {
        float Uprev0 = ws[(((size_t)g * 16 + lane - 1) * 16 + sidx) * WSF + 0];
        float q0w    = ws[(((size_t)g * 16 + lane) * 16 + sidx) * WSF + 49];
        stv = __logf(Uprev0) - __logf(q0w);
    }
    if (lane < NSEG)
        stv += ws[(((size_t)g * 16 + lane) * 16 + sidx) * WSF + 48] *
               0.6931471805599453f;
    #pragma unroll
    for (int off = 32; off; off >>= 1) stv += __shfl_xor(stv, off, 64);

    // gold score
    float gacc = 0.0f;
    #pragma unroll
    for (int it = 0; it < TT / 64; ++it) {
        int t = lane + it * 64;
        int cur = tg[t];
        int prev = (t == 0) ? START_TAG : tg[t - 1];
        gacc += trans[cur * KK + prev] + fbs[(size_t)t * KK + cur];
    }
    #pragma unroll
    for (int off = 32; off; off >>= 1) gacc += __shfl_xor(gacc, off, 64);

    if (lane == 0) {
        float gold = gacc + trans[END_TAG * KK + tg[TT - 1]];
        out[s] = __logf(val) + stv - gold;
    }
}

extern "C" void kernel_launch(void* const* d_in, const int* in_sizes, int n_in,
                              void* d_out, int out_size, void* d_ws, size_t ws_size,
                              hipStream_t stream) {
    const float* feats = (const float*)d_in[0];
    const float* trans = (const float*)d_in[1];
    const int* tags = (const int*)d_in[2];
    float* out = (float*)d_out;
    float* ws = (float*)d_ws;           // needs NPAIR*16*WSF*4 = 1.64 MB

    crf_seg_kernel<<<NPAIR, 64, 0, stream>>>(feats, trans, ws);
    crf_combine<<<BB, 64, 0, stream>>>(feats, trans, tags, ws, out);
}

// Round 11
// 168.529 us; speedup vs baseline: 1.6444x; 1.1235x over previous
//
#include <hip/hip_runtime.h>
#include <math.h>

#define KK 48
#define TT 1024
#define BB 512
#define START_TAG 46
#define END_TAG 47
#define NSEG 16
#define OWN (TT / NSEG)     // 64 owned steps per segment wave
#define WARM 16             // warm-up steps for segments 1..15 (div by DEPTH)
#define DEPTH 8             // feats prefetch depth (ring buffer)
#define NGRP (BB / 16)      // 32 sentence-groups of 16 (MFMA N=16)
#define NPAIR (NGRP * NSEG) // 512 (group, segment) blocks
#define WSF 50              // floats per (pair, sent) partial: 48 U + O + q0

typedef _Float16 h2 __attribute__((ext_vector_type(2)));
typedef _Float16 f16x4 __attribute__((ext_vector_type(4)));
typedef float f32x4 __attribute__((ext_vector_type(4)));

// MFMA intrinsic is device-only: __has_builtin is FALSE in the host pass.
#if defined(__HIP_DEVICE_COMPILE__)
  #if __has_builtin(__builtin_amdgcn_mfma_f32_16x16x16f16)
    #define MFMA16(A, B, C) __builtin_amdgcn_mfma_f32_16x16x16f16((A), (B), (C), 0, 0, 0)
  #elif __has_builtin(__builtin_amdgcn_mfma_f32_16x16x16_f16)
    #define MFMA16(A, B, C) __builtin_amdgcn_mfma_f32_16x16x16_f16((A), (B), (C), 0, 0, 0)
  #else
    #error "no 16x16x16 f16 mfma on this target"
  #endif
  #define SB() __builtin_amdgcn_sched_barrier(0)
#else
  #define MFMA16(A, B, C) (C)
  #define SB()
#endif

__device__ __forceinline__ h2 pkrtz(float a, float b) {
    return __builtin_bit_cast(h2, __builtin_amdgcn_cvt_pkrtz(a, b));
}

// ---------------------------------------------------------------------------
// R20: defeat the load-sinker. R19's DEPTH=8 ring needs 96 VGPRs but the
// kernel compiled to VGPR=76 with no scratch traffic (WRITE_SIZE == partials
// exactly): the compiler sank the prefetch loads to their uses to shrink
// live ranges, reducing effective depth to ~2 — step time 1971 cyc matches
// 2-deep service of the ~2000-cyc congested 16-sentence gather. Fix:
// sched_barrier(0) after each slot reload pins program order, forcing the
// ring to stay 8 deep (24 outstanding loads/wave). Combine kernel widened
// 64->256 thr (4 waves + LDS reduce, __syncthreads-fenced typed staging)
// for 4x latency parallelism on the gold gather. Numerics untouched.
// Predicted: seg VGPR -> ~150-180 (direct test), seg 65.7 -> 25-42 us,
// combine 17 -> 6-10 us, bench ~140-160, absmax 32. Falsifier: VGPR up but
// dur flat => DRAM-efficiency wall => transpose ef into d_ws next.
// ---------------------------------------------------------------------------

template <bool EXACT>
__device__ __forceinline__ void run_seg(const float* __restrict__ fbl,
                                        const float* __restrict__ trans,
                                        int lane, int g4, int r0, int nsteps,
                                        float (&wv)[3][4], int& esumO, int& eswmO,
                                        float& q0O) {
    // A-frags (constant): A[m][c] holds E rows 16m+(lane&15), k 16c+4*g4+j
    f16x4 Af[3][3];
    #pragma unroll
    for (int m = 0; m < 3; ++m) {
        const int row = 16 * m + (lane & 15);
        #pragma unroll
        for (int c = 0; c < 3; ++c) {
            #pragma unroll
            for (int j = 0; j < 4; ++j)
                Af[m][c][j] = (_Float16)__expf(trans[row * KK + 16 * c + 4 * g4 + j]);
        }
    }

    // B-frags (state): alpha[k = 16c + 4*g4 + j][sent = lane&15], f16
    f16x4 bf[3];
    if (EXACT) {
        #pragma unroll
        for (int c = 0; c < 3; ++c) bf[c] = (f16x4)(_Float16)0.0f;
        if (g4 == 3) bf[2][2] = (_Float16)1.0f;   // k = 32+4*3+2 = 46 = START
    } else {
        #pragma unroll
        for (int c = 0; c < 3; ++c) bf[c] = (f16x4)(_Float16)1.0f;  // all-ones
    }

    int esum = 0, eswm = 0;
    float q0v = 1.0f;

    // prefetch ring: ft[j][m] = feats[r0+st..][16m+4g4 ..+3], depth DEPTH
    f32x4 ft[DEPTH][3];
    #pragma unroll
    for (int j = 0; j < DEPTH; ++j) {
        int t = r0 + j; if (t > TT - 1) t = TT - 1;
        #pragma unroll
        for (int m = 0; m < 3; ++m)
            ft[j][m] = *(const f32x4*)(fbl + (size_t)t * KK + 16 * m + 4 * g4);
    }
    SB();   // ring fully issued before the loop body may begin

    for (int s0 = 0; s0 < nsteps; s0 += DEPTH) {
        #pragma unroll
        for (int j = 0; j < DEPTH; ++j) {
            const int st = s0 + j;
            // consume slot j
            float ef[3][4];
            #pragma unroll
            for (int m = 0; m < 3; ++m)
                #pragma unroll
                for (int r = 0; r < 4; ++r) ef[m][r] = __expf(ft[j][m][r]);
            // reload slot j with step st+DEPTH, then PIN: nothing may cross —
            // keeps these loads issued here (8 steps ahead of their use)
            {
                int tn = r0 + st + DEPTH; if (tn > TT - 1) tn = TT - 1;
                #pragma unroll
                for (int m = 0; m < 3; ++m)
                    ft[j][m] = *(const f32x4*)(fbl + (size_t)tn * KK + 16 * m + 4 * g4);
            }
            SB();
            // D = E * Alpha : 3 output tiles x 3 K-chunks
            const f32x4 z = {0.f, 0.f, 0.f, 0.f};
            f32x4 a0 = MFMA16(Af[0][0], bf[0], z);
            f32x4 a1 = MFMA16(Af[1][0], bf[0], z);
            f32x4 a2 = MFMA16(Af[2][0], bf[0], z);
            a0 = MFMA16(Af[0][1], bf[1], a0);
            a1 = MFMA16(Af[1][1], bf[1], a1);
            a2 = MFMA16(Af[2][1], bf[1], a2);
            a0 = MFMA16(Af[0][2], bf[2], a0);
            a1 = MFMA16(Af[1][2], bf[2], a1);
            a2 = MFMA16(Af[2][2], bf[2], a2);
            // alpha_raw = D .* ef
            #pragma unroll
            for (int r = 0; r < 4; ++r) {
                wv[0][r] = a0[r] * ef[0][r];
                wv[1][r] = a1[r] * ef[1][r];
                wv[2][r] = a2[r] * ef[2][r];
            }
            // per-sentence pow-2 norm: ref = row-0 raw value of own column
            float ref = __shfl(wv[0][0], lane & 15, 64);
            int eb = ((__float_as_int(ref) >> 23) & 0xff) - 127;
            esum += eb;
            float sc = __int_as_float((127 - eb) << 23);
            #pragma unroll
            for (int m = 0; m < 3; ++m)
                #pragma unroll
                for (int r = 0; r < 4; ++r) wv[m][r] *= sc;
            if (!EXACT && st == WARM - 1) { eswm = esum; q0v = ref * sc; }
            // pack scaled alpha -> next B-frags (D-layout == B-layout)
            #pragma unroll
            for (int m = 0; m < 3; ++m) {
                h2 lo = pkrtz(wv[m][0], wv[m][1]);
                h2 hi = pkrtz(wv[m][2], wv[m][3]);
                bf[m][0] = lo.x; bf[m][1] = lo.y; bf[m][2] = hi.x; bf[m][3] = hi.y;
            }
        }
    }
    esumO = esum; eswmO = eswm; q0O = q0v;
}

__global__ __launch_bounds__(64)
void crf_seg_kernel(const float* __restrict__ feats,
                    const float* __restrict__ trans,
                    float* __restrict__ ws) {
    const int pair = blockIdx.x;        // g*16 + seg
    const int g = pair >> 4;
    const int seg = pair & 15;
    const int lane = threadIdx.x & 63;
    const int g4 = lane >> 4;
    const float* fbl = feats + (size_t)(g * 16 + (lane & 15)) * TT * KK;

    float wv[3][4];
    int esum, eswm; float q0v;
    if (seg == 0) run_seg<true >(fbl, trans, lane, g4, 0, OWN, wv, esum, eswm, q0v);
    else          run_seg<false>(fbl, trans, lane, g4, seg * OWN - WARM, OWN + WARM,
                                 wv, esum, eswm, q0v);

    // partials: ws[(pair*16 + sent)*WSF + {0..47: U, 48: O, 49: q0}]
    float* base = ws + ((size_t)pair * 16 + (lane & 15)) * WSF;
    #pragma unroll
    for (int m = 0; m < 3; ++m)
        #pragma unroll
        for (int r = 0; r < 4; ++r)
            base[16 * m + 4 * g4 + r] = wv[m][r];
    if (lane < 16) {
        float* b2 = ws + ((size_t)pair * 16 + lane) * WSF;
        b2[48] = (float)(esum - eswm);   // exact: |O| << 2^24
        b2[49] = q0v;
    }
}

__global__ __launch_bounds__(256)
void crf_combine(const float* __restrict__ feats,
                 const float* __restrict__ trans,
                 const int* __restrict__ tags,
                 const float* __restrict__ ws,
                 float* __restrict__ out) {
    const int s = blockIdx.x;           // sentence
    const int g = s >> 4;
    const int sidx = s & 15;
    const int tid = threadIdx.x;
    const int lane = tid & 63;
    const int w = tid >> 6;
    const int* tg = tags + (size_t)s * TT;
    const float* fbs = feats + (size_t)s * TT * KK;

    __shared__ float red[4];

    // gold score: 1024 t's over 256 threads (4 waves), LDS reduce
    float gacc = 0.0f;
    #pragma unroll
    for (int it = 0; it < TT / 256; ++it) {
        int t = tid + it * 256;
        int cur = tg[t];
        int prev = (t == 0) ? START_TAG : tg[t - 1];
        gacc += trans[cur * KK + prev] + fbs[(size_t)t * KK + cur];
    }
    #pragma unroll
    for (int off = 32; off; off >>= 1) gacc += __shfl_xor(gacc, off, 64);
    if (lane == 0) red[w] = gacc;
    __syncthreads();

    if (w == 0) {
        // Z tail: sum_i exp(trans[END][i]) * U_last[i]
        float val = 0.0f;
        if (lane < KK)
            val = __expf(trans[END_TAG * KK + lane]) *
                  ws[(((size_t)g * 16 + 15) * 16 + sidx) * WSF + lane];
        #pragma unroll
        for (int off = 32; off; off >>= 1) val += __shfl_xor(val, off, 64);

        // ledgers + scalar stitches (lane-parallel over segments)
        float stv = 0.0f;
        if (lane >= 1 && lane < NSEG) {
            float Uprev0 = ws[(((size_t)g * 16 + lane - 1) * 16 + sidx) * WSF + 0];
            float q0w    = ws[(((size_t)g * 16 + lane) * 16 + sidx) * WSF + 49];
            stv = __logf(Uprev0) - __logf(q0w);
        }
        if (lane < NSEG)
            stv += ws[(((size_t)g * 16 + lane) * 16 + sidx) * WSF + 48] *
                   0.6931471805599453f;
        #pragma unroll
        for (int off = 32; off; off >>= 1) stv += __shfl_xor(stv, off, 64);

        if (lane == 0) {
            float gold = red[0] + red[1] + red[2] + red[3] +
                         trans[END_TAG * KK + tg[TT - 1]];
            out[s] = __logf(val) + stv - gold;
        }
    }
}

extern "C" void kernel_launch(void* const* d_in, const int* in_sizes, int n_in,
                              void* d_out, int out_size, void* d_ws, size_t ws_size,
                              hipStream_t stream) {
    const float* feats = (const float*)d_in[0];
    const float* trans = (const float*)d_in[1];
    const int* tags = (const int*)d_in[2];
    float* out = (float*)d_out;
    float* ws = (float*)d_ws;           // needs NPAIR*16*WSF*4 = 1.64 MB

    crf_seg_kernel<<<NPAIR, 64, 0, stream>>>(feats, trans, ws);
    crf_combine<<<BB, 256, 0, stream>>>(feats, trans, tags, ws, out);
}